// Round 8
// baseline (219.917 us; speedup 1.0000x reference)
//
#include <hip/hip_runtime.h>

#define N_NODES 50000
#define N_EDGES 600000
#define IN_DIM  256
#define HID     128
#define BN_EPS  1e-5f

#define SCAN_BLOCKS ((N_NODES + 255) / 256)     // 196
#define HIST_BLOCKS ((N_EDGES + 255) / 256)     // 2344
#define PREPW_BLOCKS ((IN_DIM * HID) / 256)     // 128

typedef __attribute__((ext_vector_type(8))) short bf16x8;   // 8 bf16 = 4 VGPRs
typedef __attribute__((ext_vector_type(4))) float f32x4;

__device__ __forceinline__ ushort f2bf(float f) {           // RNE fp32->bf16
    union { float f; uint u; } v; v.f = f;
    return (ushort)((v.u + 0x7FFFu + ((v.u >> 16) & 1u)) >> 16);
}
__device__ __forceinline__ float bflo(uint u) {             // low bf16 of pair -> f32
    union { uint u; float f; } v; v.u = u << 16; return v.f;
}
__device__ __forceinline__ float bfhi(uint u) {             // high bf16 of pair -> f32
    union { uint u; float f; } v; v.u = u & 0xFFFF0000u; return v.f;
}
__device__ __forceinline__ uint cvt_pk_bf16(float lo, float hi) {  // 1 VALU op, RNE
    uint r;
    asm("v_cvt_pk_bf16_f32 %0, %1, %2" : "=v"(r) : "v"(lo), "v"(hi));
    return r;
}

// ---------------------------------------------------------------------------
// zero: cnt/cursor = 0, colsum/colsumsq (256 floats) = 0   (fallback path)
// ---------------------------------------------------------------------------
__global__ __launch_bounds__(256) void zero_kernel(int* cnt, float* colstats, int n) {
    int i = blockIdx.x * 256 + threadIdx.x;
    if (i < n) cnt[i] = 0;
    if (i < 256) colstats[i] = 0.0f;
}

// ===========================================================================
// FAST PATH: fixed-stride (64) bucket CSR with USHORT node ids (6.4 MB
// bucket region -> L2-resident scatter). cursor ends = deg.
// Trailing blocks convert W -> Wt (bf16, transposed).
// ===========================================================================
__global__ __launch_bounds__(256) void fillb_prepw_kernel(const int* __restrict__ row,
                                                          const int* __restrict__ col,
                                                          int* cursor, ushort* srcs,
                                                          const float* __restrict__ W,
                                                          ushort* Wt) {
    int b = blockIdx.x;
    if (b < HIST_BLOCKS) {
        int i = b * 256 + threadIdx.x;
        if (i < N_EDGES) {
            int c = col[i];
            int pos = atomicAdd(&cursor[c], 1);
            if (pos < 64) srcs[((size_t)c << 6) + pos] = (ushort)row[i];  // clamp: P(deg>=64)~1e-25
        }
    } else {
        int i = (b - HIST_BLOCKS) * 256 + threadIdx.x;  // 0 .. 32767
        int n = i >> 8, k = i & 255;
        Wt[n * IN_DIM + k] = f2bf(W[(size_t)k * HID + n]);
    }
}

// ===========================================================================
// FALLBACK PATH (verified): hist + 3-step scan + CSR fill
// ===========================================================================
__global__ __launch_bounds__(256) void hist_prepw_kernel(const int* __restrict__ col, int* cnt,
                                                         const float* __restrict__ W, ushort* Wt) {
    int b = blockIdx.x;
    if (b < HIST_BLOCKS) {
        int i = b * 256 + threadIdx.x;
        if (i < N_EDGES) atomicAdd(&cnt[col[i]], 1);
    } else {
        int i = (b - HIST_BLOCKS) * 256 + threadIdx.x;  // 0 .. 32767
        int n = i >> 8, k = i & 255;
        Wt[n * IN_DIM + k] = f2bf(W[(size_t)k * HID + n]);
    }
}

__global__ __launch_bounds__(256) void scan_blocksum_kernel(const int* __restrict__ cnt,
                                                            int* blocksums, int n) {
    __shared__ int s[256];
    int i = blockIdx.x * 256 + threadIdx.x;
    s[threadIdx.x] = (i < n) ? cnt[i] : 0;
    __syncthreads();
    for (int off = 128; off > 0; off >>= 1) {
        if (threadIdx.x < off) s[threadIdx.x] += s[threadIdx.x + off];
        __syncthreads();
    }
    if (threadIdx.x == 0) blocksums[blockIdx.x] = s[0];
}

__global__ __launch_bounds__(256) void scan_top_kernel(int* blocksums, int nb) {
    __shared__ int s[256];
    int t = threadIdx.x;
    int v = (t < nb) ? blocksums[t] : 0;
    s[t] = v;
    __syncthreads();
    for (int off = 1; off < 256; off <<= 1) {
        int x = 0;
        if (t >= off) x = s[t - off];
        __syncthreads();
        if (t >= off) s[t] += x;
        __syncthreads();
    }
    if (t < nb) blocksums[t] = s[t] - v;   // exclusive
}

__global__ __launch_bounds__(256) void scan_final_kernel(const int* __restrict__ cnt,
                                                         const int* __restrict__ blocksums,
                                                         int* rowptr, int* cursor,
                                                         float* dis, int n) {
    __shared__ int s[256];
    int t = threadIdx.x;
    int i = blockIdx.x * 256 + t;
    int v = (i < n) ? cnt[i] : 0;
    s[t] = v;
    __syncthreads();
    for (int off = 1; off < 256; off <<= 1) {
        int x = 0;
        if (t >= off) x = s[t - off];
        __syncthreads();
        if (t >= off) s[t] += x;
        __syncthreads();
    }
    if (i < n) {
        int excl = blocksums[blockIdx.x] + s[t] - v;
        rowptr[i] = excl;
        cursor[i] = excl;
        dis[i] = rsqrtf((float)v + 1.0f);   // +1 = self loop
    }
    if (i == n - 1) rowptr[n] = N_EDGES;
}

__global__ __launch_bounds__(256) void fill_kernel(const int* __restrict__ row,
                                                   const int* __restrict__ col,
                                                   int* cursor, int* srcs, int E) {
    int i = blockIdx.x * 256 + threadIdx.x;
    if (i < E) {
        int c = col[i];
        int pos = atomicAdd(&cursor[c], 1);
        srcs[pos] = row[i];
    }
}

// ---------------------------------------------------------------------------
// GEMM via MFMA: h[M,128](bf16) = x[M,256] @ W[256,128].
// BM=64 (r4-verified layout). A-staging fp32->bf16 via v_cvt_pk_bf16_f32.
// If deg != nullptr: epilogue scales row r by rsqrt(deg[r]+1)  (dis folding).
// ---------------------------------------------------------------------------
#define LDA 40

__global__ __launch_bounds__(256) void gemm_kernel(const float* __restrict__ x,
                                                   const ushort* __restrict__ Wt,
                                                   ushort* __restrict__ h2, int M,
                                                   const int* __restrict__ deg) {
    __shared__ ushort As[64][LDA];
    __shared__ ushort Bs[128][LDA];
    const int t = threadIdx.x;
    const int row0 = blockIdx.x * 64;
    const int wave = t >> 6, lane = t & 63;
    const int lrow = lane & 15, quad = lane >> 4;

    f32x4 acc[8];
    #pragma unroll
    for (int c = 0; c < 8; c++) acc[c] = (f32x4){0.f, 0.f, 0.f, 0.f};

    const int arow = t >> 2, aq = t & 3;   // A staging: row 0..63, 8-float chunk 0..3
    const int bn = t >> 1, bh = t & 1;     // B staging: n 0..127, 16-elem half

    for (int k0 = 0; k0 < IN_DIM; k0 += 32) {
        // stage A: 64 rows x 32 k, fp32 -> bf16 via cvt_pk
        {
            int gr = row0 + arow;
            float4 f0 = make_float4(0.f, 0.f, 0.f, 0.f);
            float4 f1 = f0;
            if (gr < M) {
                const float* src = x + (size_t)gr * IN_DIM + k0 + aq * 8;
                f0 = *(const float4*)src;
                f1 = *(const float4*)(src + 4);
            }
            uint4 pk;
            pk.x = cvt_pk_bf16(f0.x, f0.y);
            pk.y = cvt_pk_bf16(f0.z, f0.w);
            pk.z = cvt_pk_bf16(f1.x, f1.y);
            pk.w = cvt_pk_bf16(f1.z, f1.w);
            *(uint4*)&As[arow][aq * 8] = pk;
        }
        // stage B: 128 n-rows x 32 k from Wt[n][k] (already bf16, k-contiguous)
        {
            const uint4* src = (const uint4*)(Wt + (size_t)bn * IN_DIM + k0 + bh * 16);
            *(uint4*)&Bs[bn][bh * 16]     = src[0];
            *(uint4*)&Bs[bn][bh * 16 + 8] = src[1];
        }
        __syncthreads();

        // A frag: A[m=lane&15][k=quad*8+j]; B frag: B[n=lane&15][k=quad*8+j]
        bf16x8 af = *(const bf16x8*)&As[wave * 16 + lrow][quad * 8];
        #pragma unroll
        for (int c = 0; c < 8; c++) {
            bf16x8 bfr = *(const bf16x8*)&Bs[c * 16 + lrow][quad * 8];
            acc[c] = __builtin_amdgcn_mfma_f32_16x16x32_bf16(af, bfr, acc[c], 0, 0, 0);
        }
        __syncthreads();
    }

    // epilogue: C/D layout col=lane&15, row=quad*4+reg; optional dis-fold; store bf16
    float disr[4];
    #pragma unroll
    for (int r = 0; r < 4; r++) {
        int gr = row0 + wave * 16 + quad * 4 + r;
        float sc = 1.0f;
        if (deg != nullptr) {
            int d = (gr < M) ? deg[gr] : 0;
            sc = rsqrtf((float)d + 1.0f);
        }
        disr[r] = sc;
    }
    #pragma unroll
    for (int c = 0; c < 8; c++) {
        #pragma unroll
        for (int r = 0; r < 4; r++) {
            int gr = row0 + wave * 16 + quad * 4 + r;
            if (gr < M) h2[(size_t)gr * HID + c * 16 + lrow] = f2bf(acc[c][r] * disr[r]);
        }
    }
}

// ---------------------------------------------------------------------------
// FAST gather: 16-deep dependency-free row-load bursts (r4-verified) with
// ushort bucket ids; 2048 blocks to test request-rate scaling past 1.9 TB/s.
// h2 rows are pre-scaled by dis (folded in GEMM).
// ---------------------------------------------------------------------------
#define GATHERC_BLOCKS 2048

__global__ __launch_bounds__(256) void gatherc_kernel(const int* __restrict__ deg,
                                                      const ushort* __restrict__ srcs,
                                                      const uint* __restrict__ h2,
                                                      float* __restrict__ out,
                                                      float* colsum, float* colsumsq) {
    const int wave = threadIdx.x >> 6, lane = threadIdx.x & 63;
    float s0 = 0.f, s1 = 0.f, q0 = 0.f, q1 = 0.f;

    for (int node = blockIdx.x * 4 + wave; node < N_NODES; node += GATHERC_BLOCKS * 4) {
        int d = deg[node]; if (d > 64) d = 64;      // memory-safety clamp
        int idx = (int)srcs[((size_t)node << 6) + lane]; // lane e holds neighbor e
        uint u = h2[(size_t)node * 64 + lane];      // self row, joins the flight
        float dn = rsqrtf((float)d + 1.0f);
        float ax = bflo(u), ay = bfhi(u);           // self-loop (pre-scaled)

        for (int e = 0; e < d; e += 16) {
            uint v[16];
            #pragma unroll
            for (int j = 0; j < 16; j++) {          // issue 16 loads, zero deps between
                int ej = e + j;
                int a = __shfl(idx, ej & 63);
                a = (ej < d) ? a : 0;               // d is wave-uniform -> scalar select
                v[j] = h2[(size_t)a * 64 + lane];
            }
            #pragma unroll
            for (int j = 0; j < 16; j++) {          // consume after all issued
                uint vv = ((e + j) < d) ? v[j] : 0u;   // uniform cond
                ax += bflo(vv); ay += bfhi(vv);
            }
        }

        ax *= dn; ay *= dn;
        ((float2*)(out + (size_t)node * HID))[lane] = make_float2(ax, ay);
        s0 += ax; s1 += ay;
        q0 = fmaf(ax, ax, q0); q1 = fmaf(ay, ay, q1);
    }

    // block-level stat reduction: cols 2*lane(+1) per lane, 4 waves
    __shared__ float rs[4][HID];
    __shared__ float rq[4][HID];
    rs[wave][lane * 2] = s0; rs[wave][lane * 2 + 1] = s1;
    rq[wave][lane * 2] = q0; rq[wave][lane * 2 + 1] = q1;
    __syncthreads();
    int t = threadIdx.x;
    if (t < HID) {
        float s = rs[0][t] + rs[1][t] + rs[2][t] + rs[3][t];
        float q = rq[0][t] + rq[1][t] + rq[2][t] + rq[3][t];
        atomicAdd(&colsum[t], s);
        atomicAdd(&colsumsq[t], q);
    }
}

// ---------------------------------------------------------------------------
// FALLBACK gather (verified): per-edge dis loads, 8-deep MLP.
// ---------------------------------------------------------------------------
#define GATHER_BLOCKS 1024

__global__ __launch_bounds__(256) void gather_kernel(const int* __restrict__ rowptr,
                                                     const int* __restrict__ srcs,
                                                     const float* __restrict__ dis,
                                                     const uint* __restrict__ h2,   // 64 uints/row
                                                     float* __restrict__ out,
                                                     float* colsum, float* colsumsq) {
    const int wave = threadIdx.x >> 6, lane = threadIdx.x & 63;
    float s0 = 0.f, s1 = 0.f, q0 = 0.f, q1 = 0.f;

    for (int node = blockIdx.x * 4 + wave; node < N_NODES; node += GATHER_BLOCKS * 4) {
        int beg = rowptr[node], end = rowptr[node + 1];
        float dn = dis[node];
        uint u = h2[(size_t)node * 64 + lane];
        float ax = bflo(u) * dn, ay = bfhi(u) * dn;    // self-loop (pre dn factor)

        int e = beg;
        for (; e + 8 <= end; e += 8) {
            int sa = srcs[e],     sb = srcs[e + 1], sc = srcs[e + 2], sd = srcs[e + 3];
            int se = srcs[e + 4], sf = srcs[e + 5], sg = srcs[e + 6], sh = srcs[e + 7];
            uint ua = h2[(size_t)sa * 64 + lane];
            uint ub = h2[(size_t)sb * 64 + lane];
            uint uc = h2[(size_t)sc * 64 + lane];
            uint ud = h2[(size_t)sd * 64 + lane];
            uint ue = h2[(size_t)se * 64 + lane];
            uint uf = h2[(size_t)sf * 64 + lane];
            uint ug = h2[(size_t)sg * 64 + lane];
            uint uh = h2[(size_t)sh * 64 + lane];
            float da = dis[sa], db = dis[sb], dc = dis[sc], dd = dis[sd];
            float de = dis[se], df = dis[sf], dg = dis[sg], dh = dis[sh];
            ax = fmaf(bflo(ua), da, ax); ay = fmaf(bfhi(ua), da, ay);
            ax = fmaf(bflo(ub), db, ax); ay = fmaf(bfhi(ub), db, ay);
            ax = fmaf(bflo(uc), dc, ax); ay = fmaf(bfhi(uc), dc, ay);
            ax = fmaf(bflo(ud), dd, ax); ay = fmaf(bfhi(ud), dd, ay);
            ax = fmaf(bflo(ue), de, ax); ay = fmaf(bfhi(ue), de, ay);
            ax = fmaf(bflo(uf), df, ax); ay = fmaf(bfhi(uf), df, ay);
            ax = fmaf(bflo(ug), dg, ax); ay = fmaf(bfhi(ug), dg, ay);
            ax = fmaf(bflo(uh), dh, ax); ay = fmaf(bfhi(uh), dh, ay);
        }
        for (; e + 4 <= end; e += 4) {
            int sa = srcs[e], sb = srcs[e + 1], sc = srcs[e + 2], sd = srcs[e + 3];
            uint ua = h2[(size_t)sa * 64 + lane];
            uint ub = h2[(size_t)sb * 64 + lane];
            uint uc = h2[(size_t)sc * 64 + lane];
            uint ud = h2[(size_t)sd * 64 + lane];
            float da = dis[sa], db = dis[sb], dc = dis[sc], dd = dis[sd];
            ax = fmaf(bflo(ua), da, ax); ay = fmaf(bfhi(ua), da, ay);
            ax = fmaf(bflo(ub), db, ax); ay = fmaf(bfhi(ub), db, ay);
            ax = fmaf(bflo(uc), dc, ax); ay = fmaf(bfhi(uc), dc, ay);
            ax = fmaf(bflo(ud), dd, ax); ay = fmaf(bfhi(ud), dd, ay);
        }
        for (; e < end; e++) {
            int s = srcs[e];
            uint uv = h2[(size_t)s * 64 + lane];
            float ds = dis[s];
            ax = fmaf(bflo(uv), ds, ax); ay = fmaf(bfhi(uv), ds, ay);
        }
        ax *= dn; ay *= dn;
        ((float2*)(out + (size_t)node * HID))[lane] = make_float2(ax, ay);
        s0 += ax; s1 += ay;
        q0 = fmaf(ax, ax, q0); q1 = fmaf(ay, ay, q1);
    }

    __shared__ float rs[4][HID];
    __shared__ float rq[4][HID];
    rs[wave][lane * 2] = s0; rs[wave][lane * 2 + 1] = s1;
    rq[wave][lane * 2] = q0; rq[wave][lane * 2 + 1] = q1;
    __syncthreads();
    int t = threadIdx.x;
    if (t < HID) {
        float s = rs[0][t] + rs[1][t] + rs[2][t] + rs[3][t];
        float q = rq[0][t] + rq[1][t] + rq[2][t] + rq[3][t];
        atomicAdd(&colsum[t], s);
        atomicAdd(&colsumsq[t], q);
    }
}

// ---------------------------------------------------------------------------
// BN (training stats, biased var) + ReLU, in place. (bias b cancels in BN)
// ---------------------------------------------------------------------------
__global__ __launch_bounds__(256) void bn_relu_kernel(float* __restrict__ out,
                                                      const float* __restrict__ colsum,
                                                      const float* __restrict__ colsumsq,
                                                      const float* __restrict__ gamma,
                                                      const float* __restrict__ beta, int M) {
    size_t i = (size_t)blockIdx.x * 256 + threadIdx.x;
    size_t total = (size_t)M * (HID / 4);
    if (i >= total) return;
    int c4 = (int)((i & (HID / 4 - 1)) * 4);
    float4 v = ((const float4*)out)[i];
    float vv[4] = {v.x, v.y, v.z, v.w};
    float res[4];
    const float invN = 1.0f / (float)M;
    #pragma unroll
    for (int j = 0; j < 4; j++) {
        int c = c4 + j;
        float mean = colsum[c] * invN;
        float var  = colsumsq[c] * invN - mean * mean;
        var = fmaxf(var, 0.0f);
        float sc = gamma[c] * rsqrtf(var + BN_EPS);
        res[j] = fmaxf(0.0f, (vv[j] - mean) * sc + beta[c]);
    }
    ((float4*)out)[i] = make_float4(res[0], res[1], res[2], res[3]);
}

// ---------------------------------------------------------------------------
extern "C" void kernel_launch(void* const* d_in, const int* in_sizes, int n_in,
                              void* d_out, int out_size, void* d_ws, size_t ws_size,
                              hipStream_t stream) {
    const float* x     = (const float*)d_in[0];
    const int*   ei    = (const int*)  d_in[1];   // [2,E] flat: row(src) then col(dst)
    const float* W     = (const float*)d_in[2];
    // d_in[3] = b: cancels inside BatchNorm -> unused
    const float* gamma = (const float*)d_in[4];
    const float* beta  = (const float*)d_in[5];
    float* out = (float*)d_out;

    const int* row = ei;
    const int* col = ei + N_EDGES;

    const size_t FAST_NEED = (size_t)4866816u * 4u;   // 19.47 MB

    if (ws_size >= FAST_NEED) {
        // ---------- fast path: ushort bucket CSR, dis folded into GEMM ----------
        int*    cursor   = (int*)d_ws;                        // [50000] -> deg after fill
        ushort* srcs     = (ushort*)((int*)d_ws + 50176);     // [50000*64] ushort bucket CSR
        ushort* Wt       = (ushort*)((int*)d_ws + 1650176);   // [128*256] bf16
        ushort* h2       = (ushort*)((int*)d_ws + 1666560);   // [50000*128] bf16, pre-scaled
        float*  colsum   = (float*)d_ws + 4866560;            // [128]
        float*  colsumsq = (float*)d_ws + 4866688;            // [128]

        // zero via graph-capturable memset nodes
        hipMemsetAsync(cursor, 0, (size_t)N_NODES * sizeof(int), stream);
        hipMemsetAsync(colsum, 0, 256 * sizeof(float), stream);   // colsum+colsumsq contiguous

        fillb_prepw_kernel<<<HIST_BLOCKS + PREPW_BLOCKS, 256, 0, stream>>>(row, col, cursor,
                                                                           srcs, W, Wt);

        gemm_kernel<<<(N_NODES + 63) / 64, 256, 0, stream>>>(x, Wt, h2, N_NODES, cursor);

        gatherc_kernel<<<GATHERC_BLOCKS, 256, 0, stream>>>(cursor, srcs, (const uint*)h2, out,
                                                           colsum, colsumsq);

        size_t total = (size_t)N_NODES * (HID / 4);
        bn_relu_kernel<<<(int)((total + 255) / 256), 256, 0, stream>>>(out, colsum, colsumsq,
                                                                       gamma, beta, N_NODES);
    } else {
        // ---------- fallback: verified CSR path ----------
        int*    cnt       = (int*)d_ws;                        // [50000]
        float*  dis       = (float*)d_ws + 50000;              // [50000]
        int*    rowptr    = (int*)d_ws + 100000;               // [50001]
        int*    cursor    = (int*)d_ws + 150016;               // [50000]
        int*    blocksums = (int*)d_ws + 200016;               // [256]
        int*    srcs      = (int*)d_ws + 200272;               // [600000]
        ushort* Wt        = (ushort*)((int*)d_ws + 800272);    // [128*256] bf16
        ushort* h2        = (ushort*)((int*)d_ws + 816656);    // [50000*128] bf16
        float*  colsum    = (float*)d_ws + 4016656;            // [128]
        float*  colsumsq  = (float*)d_ws + 4016784;            // [128]

        zero_kernel<<<(N_NODES + 255) / 256, 256, 0, stream>>>(cnt, colsum, N_NODES);

        hist_prepw_kernel<<<HIST_BLOCKS + PREPW_BLOCKS, 256, 0, stream>>>(col, cnt, W, Wt);

        scan_blocksum_kernel<<<SCAN_BLOCKS, 256, 0, stream>>>(cnt, blocksums, N_NODES);
        scan_top_kernel<<<1, 256, 0, stream>>>(blocksums, SCAN_BLOCKS);
        scan_final_kernel<<<SCAN_BLOCKS, 256, 0, stream>>>(cnt, blocksums, rowptr, cursor, dis,
                                                           N_NODES);

        fill_kernel<<<HIST_BLOCKS, 256, 0, stream>>>(row, col, cursor, srcs, N_EDGES);

        gemm_kernel<<<(N_NODES + 63) / 64, 256, 0, stream>>>(x, Wt, h2, N_NODES, nullptr);

        gather_kernel<<<GATHER_BLOCKS, 256, 0, stream>>>(rowptr, srcs, dis, (const uint*)h2, out,
                                                         colsum, colsumsq);

        size_t total = (size_t)N_NODES * (HID / 4);
        bn_relu_kernel<<<(int)((total + 255) / 256), 256, 0, stream>>>(out, colsum, colsumsq,
                                                                       gamma, beta, N_NODES);
    }
}

// Round 10
// 203.481 us; speedup vs baseline: 1.0808x; 1.0808x over previous
//
#include <hip/hip_runtime.h>

#define N_NODES 50000
#define N_EDGES 600000
#define IN_DIM  256
#define HID     128
#define BN_EPS  1e-5f

#define SCAN_BLOCKS ((N_NODES + 255) / 256)     // 196
#define HIST_BLOCKS ((N_EDGES + 255) / 256)     // 2344
#define PREPW_BLOCKS ((IN_DIM * HID) / 256)     // 128

typedef __attribute__((ext_vector_type(8))) short bf16x8;   // 8 bf16 = 4 VGPRs
typedef __attribute__((ext_vector_type(4))) float f32x4;

__device__ __forceinline__ ushort f2bf(float f) {           // RNE fp32->bf16
    union { float f; uint u; } v; v.f = f;
    return (ushort)((v.u + 0x7FFFu + ((v.u >> 16) & 1u)) >> 16);
}
__device__ __forceinline__ float bflo(uint u) {             // low bf16 of pair -> f32
    union { uint u; float f; } v; v.u = u << 16; return v.f;
}
__device__ __forceinline__ float bfhi(uint u) {             // high bf16 of pair -> f32
    union { uint u; float f; } v; v.u = u & 0xFFFF0000u; return v.f;
}
__device__ __forceinline__ uint cvt_pk_bf16(float lo, float hi) {  // 1 VALU op, RNE
    uint r;
    asm("v_cvt_pk_bf16_f32 %0, %1, %2" : "=v"(r) : "v"(lo), "v"(hi));
    return r;
}

// ---------------------------------------------------------------------------
// zero: cnt/cursor = 0, colsum/colsumsq (256 floats) = 0   (fallback path)
// ---------------------------------------------------------------------------
__global__ __launch_bounds__(256) void zero_kernel(int* cnt, float* colstats, int n) {
    int i = blockIdx.x * 256 + threadIdx.x;
    if (i < n) cnt[i] = 0;
    if (i < 256) colstats[i] = 0.0f;
}

// ===========================================================================
// FAST PATH: fixed-stride (64) bucket CSR (int ids — r4/r7 verified).
// srcs[col*64 + pos] = row, pos = atomicAdd(cursor[col]).  cursor ends = deg.
// Trailing blocks convert W -> Wt (bf16, transposed).
// ===========================================================================
__global__ __launch_bounds__(256) void fillb_prepw_kernel(const int* __restrict__ row,
                                                          const int* __restrict__ col,
                                                          int* cursor, int* srcs,
                                                          const float* __restrict__ W,
                                                          ushort* Wt) {
    int b = blockIdx.x;
    if (b < HIST_BLOCKS) {
        int i = b * 256 + threadIdx.x;
        if (i < N_EDGES) {
            int c = col[i];
            int pos = atomicAdd(&cursor[c], 1);
            if (pos < 64) srcs[((size_t)c << 6) + pos] = row[i];   // clamp: P(deg>=64)~1e-25
        }
    } else {
        int i = (b - HIST_BLOCKS) * 256 + threadIdx.x;  // 0 .. 32767
        int n = i >> 8, k = i & 255;
        Wt[n * IN_DIM + k] = f2bf(W[(size_t)k * HID + n]);
    }
}

// ===========================================================================
// FALLBACK PATH (verified): hist + 3-step scan + CSR fill
// ===========================================================================
__global__ __launch_bounds__(256) void hist_prepw_kernel(const int* __restrict__ col, int* cnt,
                                                         const float* __restrict__ W, ushort* Wt) {
    int b = blockIdx.x;
    if (b < HIST_BLOCKS) {
        int i = b * 256 + threadIdx.x;
        if (i < N_EDGES) atomicAdd(&cnt[col[i]], 1);
    } else {
        int i = (b - HIST_BLOCKS) * 256 + threadIdx.x;  // 0 .. 32767
        int n = i >> 8, k = i & 255;
        Wt[n * IN_DIM + k] = f2bf(W[(size_t)k * HID + n]);
    }
}

__global__ __launch_bounds__(256) void scan_blocksum_kernel(const int* __restrict__ cnt,
                                                            int* blocksums, int n) {
    __shared__ int s[256];
    int i = blockIdx.x * 256 + threadIdx.x;
    s[threadIdx.x] = (i < n) ? cnt[i] : 0;
    __syncthreads();
    for (int off = 128; off > 0; off >>= 1) {
        if (threadIdx.x < off) s[threadIdx.x] += s[threadIdx.x + off];
        __syncthreads();
    }
    if (threadIdx.x == 0) blocksums[blockIdx.x] = s[0];
}

__global__ __launch_bounds__(256) void scan_top_kernel(int* blocksums, int nb) {
    __shared__ int s[256];
    int t = threadIdx.x;
    int v = (t < nb) ? blocksums[t] : 0;
    s[t] = v;
    __syncthreads();
    for (int off = 1; off < 256; off <<= 1) {
        int x = 0;
        if (t >= off) x = s[t - off];
        __syncthreads();
        if (t >= off) s[t] += x;
        __syncthreads();
    }
    if (t < nb) blocksums[t] = s[t] - v;   // exclusive
}

__global__ __launch_bounds__(256) void scan_final_kernel(const int* __restrict__ cnt,
                                                         const int* __restrict__ blocksums,
                                                         int* rowptr, int* cursor,
                                                         float* dis, int n) {
    __shared__ int s[256];
    int t = threadIdx.x;
    int i = blockIdx.x * 256 + t;
    int v = (i < n) ? cnt[i] : 0;
    s[t] = v;
    __syncthreads();
    for (int off = 1; off < 256; off <<= 1) {
        int x = 0;
        if (t >= off) x = s[t - off];
        __syncthreads();
        if (t >= off) s[t] += x;
        __syncthreads();
    }
    if (i < n) {
        int excl = blocksums[blockIdx.x] + s[t] - v;
        rowptr[i] = excl;
        cursor[i] = excl;
        dis[i] = rsqrtf((float)v + 1.0f);   // +1 = self loop
    }
    if (i == n - 1) rowptr[n] = N_EDGES;
}

__global__ __launch_bounds__(256) void fill_kernel(const int* __restrict__ row,
                                                   const int* __restrict__ col,
                                                   int* cursor, int* srcs, int E) {
    int i = blockIdx.x * 256 + threadIdx.x;
    if (i < E) {
        int c = col[i];
        int pos = atomicAdd(&cursor[c], 1);
        srcs[pos] = row[i];
    }
}

// ---------------------------------------------------------------------------
// GEMM via MFMA: h[M,128](bf16) = x[M,256] @ W[256,128].
// BM=128 (2 m-tiles/wave, 16 MFMA/k-step) with single-pass cvt_pk A-staging
// (r6's tile retried WITHOUT its expensive bit-twiddle staging).
// If deg != nullptr: epilogue scales row r by rsqrt(deg[r]+1)  (dis folding).
// ---------------------------------------------------------------------------
#define LDA 40

__global__ __launch_bounds__(256) void gemm_kernel(const float* __restrict__ x,
                                                   const ushort* __restrict__ Wt,
                                                   ushort* __restrict__ h2, int M,
                                                   const int* __restrict__ deg) {
    __shared__ ushort As[128][LDA];
    __shared__ ushort Bs[128][LDA];
    const int t = threadIdx.x;
    const int row0 = blockIdx.x * 128;
    const int wave = t >> 6, lane = t & 63;
    const int lrow = lane & 15, quad = lane >> 4;

    f32x4 acc0[8], acc1[8];
    #pragma unroll
    for (int c = 0; c < 8; c++) {
        acc0[c] = (f32x4){0.f, 0.f, 0.f, 0.f};
        acc1[c] = (f32x4){0.f, 0.f, 0.f, 0.f};
    }

    const int arow = t >> 1, aq = t & 1;   // A staging: row 0..127, 16-float half
    const int bn = t >> 1, bh = t & 1;     // B staging: n 0..127, 16-elem half

    for (int k0 = 0; k0 < IN_DIM; k0 += 32) {
        // stage A: 128 rows x 32 k, single pass, fp32 -> bf16 via cvt_pk
        {
            int gr = row0 + arow;
            float4 f0 = make_float4(0.f, 0.f, 0.f, 0.f);
            float4 f1 = f0, f2 = f0, f3 = f0;
            if (gr < M) {
                const float* src = x + (size_t)gr * IN_DIM + k0 + aq * 16;
                f0 = *(const float4*)src;
                f1 = *(const float4*)(src + 4);
                f2 = *(const float4*)(src + 8);
                f3 = *(const float4*)(src + 12);
            }
            uint4 pk0, pk1;
            pk0.x = cvt_pk_bf16(f0.x, f0.y);
            pk0.y = cvt_pk_bf16(f0.z, f0.w);
            pk0.z = cvt_pk_bf16(f1.x, f1.y);
            pk0.w = cvt_pk_bf16(f1.z, f1.w);
            pk1.x = cvt_pk_bf16(f2.x, f2.y);
            pk1.y = cvt_pk_bf16(f2.z, f2.w);
            pk1.z = cvt_pk_bf16(f3.x, f3.y);
            pk1.w = cvt_pk_bf16(f3.z, f3.w);
            *(uint4*)&As[arow][aq * 16]     = pk0;
            *(uint4*)&As[arow][aq * 16 + 8] = pk1;
        }
        // stage B: 128 n-rows x 32 k from Wt[n][k] (already bf16, k-contiguous)
        {
            const uint4* src = (const uint4*)(Wt + (size_t)bn * IN_DIM + k0 + bh * 16);
            *(uint4*)&Bs[bn][bh * 16]     = src[0];
            *(uint4*)&Bs[bn][bh * 16 + 8] = src[1];
        }
        __syncthreads();

        // A frags: rows wave*32 + {0,16} + lrow; B frag: B[n=lane&15][k=quad*8+j]
        bf16x8 af0 = *(const bf16x8*)&As[wave * 32 + lrow][quad * 8];
        bf16x8 af1 = *(const bf16x8*)&As[wave * 32 + 16 + lrow][quad * 8];
        #pragma unroll
        for (int c = 0; c < 8; c++) {
            bf16x8 bfr = *(const bf16x8*)&Bs[c * 16 + lrow][quad * 8];
            acc0[c] = __builtin_amdgcn_mfma_f32_16x16x32_bf16(af0, bfr, acc0[c], 0, 0, 0);
            acc1[c] = __builtin_amdgcn_mfma_f32_16x16x32_bf16(af1, bfr, acc1[c], 0, 0, 0);
        }
        __syncthreads();
    }

    // epilogue: C/D layout col=lane&15, row=quad*4+reg; optional dis-fold; store bf16
    float disr0[4], disr1[4];
    #pragma unroll
    for (int r = 0; r < 4; r++) {
        int gr0 = row0 + wave * 32 + quad * 4 + r;
        int gr1 = gr0 + 16;
        float sc0 = 1.0f, sc1 = 1.0f;
        if (deg != nullptr) {
            int d0 = (gr0 < M) ? deg[gr0] : 0;
            int d1 = (gr1 < M) ? deg[gr1] : 0;
            sc0 = rsqrtf((float)d0 + 1.0f);
            sc1 = rsqrtf((float)d1 + 1.0f);
        }
        disr0[r] = sc0; disr1[r] = sc1;
    }
    #pragma unroll
    for (int c = 0; c < 8; c++) {
        #pragma unroll
        for (int r = 0; r < 4; r++) {
            int gr0 = row0 + wave * 32 + quad * 4 + r;
            int gr1 = gr0 + 16;
            if (gr0 < M) h2[(size_t)gr0 * HID + c * 16 + lrow] = f2bf(acc0[c][r] * disr0[r]);
            if (gr1 < M) h2[(size_t)gr1 * HID + c * 16 + lrow] = f2bf(acc1[c][r] * disr1[r]);
        }
    }
}

// ---------------------------------------------------------------------------
// FAST gather (r4/r7-verified): 16-deep dependency-free row-load bursts,
// int bucket ids, 1024 blocks (2048 regresses ~+16us — r8 datum).
// h2 rows are pre-scaled by dis (folded in GEMM).
// ---------------------------------------------------------------------------
#define GATHERC_BLOCKS 1024

__global__ __launch_bounds__(256) void gatherc_kernel(const int* __restrict__ deg,
                                                      const int* __restrict__ srcs,
                                                      const uint* __restrict__ h2,
                                                      float* __restrict__ out,
                                                      float* colsum, float* colsumsq) {
    const int wave = threadIdx.x >> 6, lane = threadIdx.x & 63;
    float s0 = 0.f, s1 = 0.f, q0 = 0.f, q1 = 0.f;

    for (int node = blockIdx.x * 4 + wave; node < N_NODES; node += GATHERC_BLOCKS * 4) {
        int d = deg[node]; if (d > 64) d = 64;      // memory-safety clamp
        int idx = srcs[((size_t)node << 6) + lane]; // lane e holds neighbor e
        uint u = h2[(size_t)node * 64 + lane];      // self row, joins the flight
        float dn = rsqrtf((float)d + 1.0f);
        float ax = bflo(u), ay = bfhi(u);           // self-loop (pre-scaled)

        for (int e = 0; e < d; e += 16) {
            uint v[16];
            #pragma unroll
            for (int j = 0; j < 16; j++) {          // issue 16 loads, zero deps between
                int ej = e + j;
                int a = __shfl(idx, ej & 63);
                a = (ej < d) ? a : 0;               // d is wave-uniform -> scalar select
                v[j] = h2[(size_t)a * 64 + lane];
            }
            #pragma unroll
            for (int j = 0; j < 16; j++) {          // consume after all issued
                uint vv = ((e + j) < d) ? v[j] : 0u;   // uniform cond
                ax += bflo(vv); ay += bfhi(vv);
            }
        }

        ax *= dn; ay *= dn;
        ((float2*)(out + (size_t)node * HID))[lane] = make_float2(ax, ay);
        s0 += ax; s1 += ay;
        q0 = fmaf(ax, ax, q0); q1 = fmaf(ay, ay, q1);
    }

    // block-level stat reduction: cols 2*lane(+1) per lane, 4 waves
    __shared__ float rs[4][HID];
    __shared__ float rq[4][HID];
    rs[wave][lane * 2] = s0; rs[wave][lane * 2 + 1] = s1;
    rq[wave][lane * 2] = q0; rq[wave][lane * 2 + 1] = q1;
    __syncthreads();
    int t = threadIdx.x;
    if (t < HID) {
        float s = rs[0][t] + rs[1][t] + rs[2][t] + rs[3][t];
        float q = rq[0][t] + rq[1][t] + rq[2][t] + rq[3][t];
        atomicAdd(&colsum[t], s);
        atomicAdd(&colsumsq[t], q);
    }
}

// ---------------------------------------------------------------------------
// FALLBACK gather (verified): per-edge dis loads, 8-deep MLP.
// ---------------------------------------------------------------------------
#define GATHER_BLOCKS 1024

__global__ __launch_bounds__(256) void gather_kernel(const int* __restrict__ rowptr,
                                                     const int* __restrict__ srcs,
                                                     const float* __restrict__ dis,
                                                     const uint* __restrict__ h2,   // 64 uints/row
                                                     float* __restrict__ out,
                                                     float* colsum, float* colsumsq) {
    const int wave = threadIdx.x >> 6, lane = threadIdx.x & 63;
    float s0 = 0.f, s1 = 0.f, q0 = 0.f, q1 = 0.f;

    for (int node = blockIdx.x * 4 + wave; node < N_NODES; node += GATHER_BLOCKS * 4) {
        int beg = rowptr[node], end = rowptr[node + 1];
        float dn = dis[node];
        uint u = h2[(size_t)node * 64 + lane];
        float ax = bflo(u) * dn, ay = bfhi(u) * dn;    // self-loop (pre dn factor)

        int e = beg;
        for (; e + 8 <= end; e += 8) {
            int sa = srcs[e],     sb = srcs[e + 1], sc = srcs[e + 2], sd = srcs[e + 3];
            int se = srcs[e + 4], sf = srcs[e + 5], sg = srcs[e + 6], sh = srcs[e + 7];
            uint ua = h2[(size_t)sa * 64 + lane];
            uint ub = h2[(size_t)sb * 64 + lane];
            uint uc = h2[(size_t)sc * 64 + lane];
            uint ud = h2[(size_t)sd * 64 + lane];
            uint ue = h2[(size_t)se * 64 + lane];
            uint uf = h2[(size_t)sf * 64 + lane];
            uint ug = h2[(size_t)sg * 64 + lane];
            uint uh = h2[(size_t)sh * 64 + lane];
            float da = dis[sa], db = dis[sb], dc = dis[sc], dd = dis[sd];
            float de = dis[se], df = dis[sf], dg = dis[sg], dh = dis[sh];
            ax = fmaf(bflo(ua), da, ax); ay = fmaf(bfhi(ua), da, ay);
            ax = fmaf(bflo(ub), db, ax); ay = fmaf(bfhi(ub), db, ay);
            ax = fmaf(bflo(uc), dc, ax); ay = fmaf(bfhi(uc), dc, ay);
            ax = fmaf(bflo(ud), dd, ax); ay = fmaf(bfhi(ud), dd, ay);
            ax = fmaf(bflo(ue), de, ax); ay = fmaf(bfhi(ue), de, ay);
            ax = fmaf(bflo(uf), df, ax); ay = fmaf(bfhi(uf), df, ay);
            ax = fmaf(bflo(ug), dg, ax); ay = fmaf(bfhi(ug), dg, ay);
            ax = fmaf(bflo(uh), dh, ax); ay = fmaf(bfhi(uh), dh, ay);
        }
        for (; e + 4 <= end; e += 4) {
            int sa = srcs[e], sb = srcs[e + 1], sc = srcs[e + 2], sd = srcs[e + 3];
            uint ua = h2[(size_t)sa * 64 + lane];
            uint ub = h2[(size_t)sb * 64 + lane];
            uint uc = h2[(size_t)sc * 64 + lane];
            uint ud = h2[(size_t)sd * 64 + lane];
            float da = dis[sa], db = dis[sb], dc = dis[sc], dd = dis[sd];
            ax = fmaf(bflo(ua), da, ax); ay = fmaf(bfhi(ua), da, ay);
            ax = fmaf(bflo(ub), db, ax); ay = fmaf(bfhi(ub), db, ay);
            ax = fmaf(bflo(uc), dc, ax); ay = fmaf(bfhi(uc), dc, ay);
            ax = fmaf(bflo(ud), dd, ax); ay = fmaf(bfhi(ud), dd, ay);
        }
        for (; e < end; e++) {
            int s = srcs[e];
            uint uv = h2[(size_t)s * 64 + lane];
            float ds = dis[s];
            ax = fmaf(bflo(uv), ds, ax); ay = fmaf(bfhi(uv), ds, ay);
        }
        ax *= dn; ay *= dn;
        ((float2*)(out + (size_t)node * HID))[lane] = make_float2(ax, ay);
        s0 += ax; s1 += ay;
        q0 = fmaf(ax, ax, q0); q1 = fmaf(ay, ay, q1);
    }

    __shared__ float rs[4][HID];
    __shared__ float rq[4][HID];
    rs[wave][lane * 2] = s0; rs[wave][lane * 2 + 1] = s1;
    rq[wave][lane * 2] = q0; rq[wave][lane * 2 + 1] = q1;
    __syncthreads();
    int t = threadIdx.x;
    if (t < HID) {
        float s = rs[0][t] + rs[1][t] + rs[2][t] + rs[3][t];
        float q = rq[0][t] + rq[1][t] + rq[2][t] + rq[3][t];
        atomicAdd(&colsum[t], s);
        atomicAdd(&colsumsq[t], q);
    }
}

// ---------------------------------------------------------------------------
// BN (training stats, biased var) + ReLU, in place. (bias b cancels in BN)
// ---------------------------------------------------------------------------
__global__ __launch_bounds__(256) void bn_relu_kernel(float* __restrict__ out,
                                                      const float* __restrict__ colsum,
                                                      const float* __restrict__ colsumsq,
                                                      const float* __restrict__ gamma,
                                                      const float* __restrict__ beta, int M) {
    size_t i = (size_t)blockIdx.x * 256 + threadIdx.x;
    size_t total = (size_t)M * (HID / 4);
    if (i >= total) return;
    int c4 = (int)((i & (HID / 4 - 1)) * 4);
    float4 v = ((const float4*)out)[i];
    float vv[4] = {v.x, v.y, v.z, v.w};
    float res[4];
    const float invN = 1.0f / (float)M;
    #pragma unroll
    for (int j = 0; j < 4; j++) {
        int c = c4 + j;
        float mean = colsum[c] * invN;
        float var  = colsumsq[c] * invN - mean * mean;
        var = fmaxf(var, 0.0f);
        float sc = gamma[c] * rsqrtf(var + BN_EPS);
        res[j] = fmaxf(0.0f, (vv[j] - mean) * sc + beta[c]);
    }
    ((float4*)out)[i] = make_float4(res[0], res[1], res[2], res[3]);
}

// ---------------------------------------------------------------------------
extern "C" void kernel_launch(void* const* d_in, const int* in_sizes, int n_in,
                              void* d_out, int out_size, void* d_ws, size_t ws_size,
                              hipStream_t stream) {
    const float* x     = (const float*)d_in[0];
    const int*   ei    = (const int*)  d_in[1];   // [2,E] flat: row(src) then col(dst)
    const float* W     = (const float*)d_in[2];
    // d_in[3] = b: cancels inside BatchNorm -> unused
    const float* gamma = (const float*)d_in[4];
    const float* beta  = (const float*)d_in[5];
    float* out = (float*)d_out;

    const int* row = ei;
    const int* col = ei + N_EDGES;

    const size_t FAST_NEED = (size_t)6466816u * 4u;   // 25.87 MB

    if (ws_size >= FAST_NEED) {
        // ---------- fast path: bucket CSR, dis folded into GEMM ----------
        int*    cursor   = (int*)d_ws;                       // [50000] -> deg after fill
        int*    srcs     = (int*)d_ws + 50176;               // [50000*64] bucket CSR
        ushort* Wt       = (ushort*)((int*)d_ws + 3250176);  // [128*256] bf16
        ushort* h2       = (ushort*)((int*)d_ws + 3266560);  // [50000*128] bf16, pre-scaled
        float*  colsum   = (float*)d_ws + 6466560;           // [128]
        float*  colsumsq = (float*)d_ws + 6466688;           // [128]

        // zero via graph-capturable memset nodes
        hipMemsetAsync(cursor, 0, (size_t)N_NODES * sizeof(int), stream);
        hipMemsetAsync(colsum, 0, 256 * sizeof(float), stream);   // colsum+colsumsq contiguous

        fillb_prepw_kernel<<<HIST_BLOCKS + PREPW_BLOCKS, 256, 0, stream>>>(row, col, cursor,
                                                                           srcs, W, Wt);

        gemm_kernel<<<(N_NODES + 127) / 128, 256, 0, stream>>>(x, Wt, h2, N_NODES, cursor);

        gatherc_kernel<<<GATHERC_BLOCKS, 256, 0, stream>>>(cursor, srcs, (const uint*)h2, out,
                                                           colsum, colsumsq);

        size_t total = (size_t)N_NODES * (HID / 4);
        bn_relu_kernel<<<(int)((total + 255) / 256), 256, 0, stream>>>(out, colsum, colsumsq,
                                                                       gamma, beta, N_NODES);
    } else {
        // ---------- fallback: verified CSR path ----------
        int*    cnt       = (int*)d_ws;                        // [50000]
        float*  dis       = (float*)d_ws + 50000;              // [50000]
        int*    rowptr    = (int*)d_ws + 100000;               // [50001]
        int*    cursor    = (int*)d_ws + 150016;               // [50000]
        int*    blocksums = (int*)d_ws + 200016;               // [256]
        int*    srcs      = (int*)d_ws + 200272;               // [600000]
        ushort* Wt        = (ushort*)((int*)d_ws + 800272);    // [128*256] bf16
        ushort* h2        = (ushort*)((int*)d_ws + 816656);    // [50000*128] bf16
        float*  colsum    = (float*)d_ws + 4016656;            // [128]
        float*  colsumsq  = (float*)d_ws + 4016784;            // [128]

        zero_kernel<<<(N_NODES + 255) / 256, 256, 0, stream>>>(cnt, colsum, N_NODES);

        hist_prepw_kernel<<<HIST_BLOCKS + PREPW_BLOCKS, 256, 0, stream>>>(col, cnt, W, Wt);

        scan_blocksum_kernel<<<SCAN_BLOCKS, 256, 0, stream>>>(cnt, blocksums, N_NODES);
        scan_top_kernel<<<1, 256, 0, stream>>>(blocksums, SCAN_BLOCKS);
        scan_final_kernel<<<SCAN_BLOCKS, 256, 0, stream>>>(cnt, blocksums, rowptr, cursor, dis,
                                                           N_NODES);

        fill_kernel<<<HIST_BLOCKS, 256, 0, stream>>>(row, col, cursor, srcs, N_EDGES);

        // fallback keeps BM=128 gemm (mapping verified in r6 run, passed)
        gemm_kernel<<<(N_NODES + 127) / 128, 256, 0, stream>>>(x, Wt, h2, N_NODES, nullptr);

        gather_kernel<<<GATHER_BLOCKS, 256, 0, stream>>>(rowptr, srcs, dis, (const uint*)h2, out,
                                                         colsum, colsumsq);

        size_t total = (size_t)N_NODES * (HID / 4);
        bn_relu_kernel<<<(int)((total + 255) / 256), 256, 0, stream>>>(out, colsum, colsumsq,
                                                                       gamma, beta, N_NODES);
    }
}

// Round 11
// 199.986 us; speedup vs baseline: 1.0997x; 1.0175x over previous
//
#include <hip/hip_runtime.h>

#define N_NODES 50000
#define N_EDGES 600000
#define IN_DIM  256
#define HID     128
#define BN_EPS  1e-5f

#define SCAN_BLOCKS ((N_NODES + 255) / 256)     // 196
#define HIST_BLOCKS ((N_EDGES + 255) / 256)     // 2344
#define PREPW_BLOCKS ((IN_DIM * HID) / 256)     // 128

typedef __attribute__((ext_vector_type(8))) short bf16x8;   // 8 bf16 = 4 VGPRs
typedef __attribute__((ext_vector_type(4))) float f32x4;

__device__ __forceinline__ ushort f2bf(float f) {           // RNE fp32->bf16
    union { float f; uint u; } v; v.f = f;
    return (ushort)((v.u + 0x7FFFu + ((v.u >> 16) & 1u)) >> 16);
}
__device__ __forceinline__ float bflo(uint u) {             // low bf16 of pair -> f32
    union { uint u; float f; } v; v.u = u << 16; return v.f;
}
__device__ __forceinline__ float bfhi(uint u) {             // high bf16 of pair -> f32
    union { uint u; float f; } v; v.u = u & 0xFFFF0000u; return v.f;
}

// ---------------------------------------------------------------------------
// zero: cnt/cursor = 0, colsum/colsumsq (256 floats) = 0
// (r4-verified; memset-node variant measured equal within noise)
// ---------------------------------------------------------------------------
__global__ __launch_bounds__(256) void zero_kernel(int* cnt, float* colstats, int n) {
    int i = blockIdx.x * 256 + threadIdx.x;
    if (i < n) cnt[i] = 0;
    if (i < 256) colstats[i] = 0.0f;
}

// ===========================================================================
// FAST PATH: fixed-stride (64) bucket CSR — no hist, no scan.
// srcs[col*64 + pos] = row, pos = atomicAdd(cursor[col]).  cursor ends = deg.
// Trailing blocks convert W -> Wt (bf16, transposed).
// ===========================================================================
__global__ __launch_bounds__(256) void fillb_prepw_kernel(const int* __restrict__ row,
                                                          const int* __restrict__ col,
                                                          int* cursor, int* srcs,
                                                          const float* __restrict__ W,
                                                          ushort* Wt) {
    int b = blockIdx.x;
    if (b < HIST_BLOCKS) {
        int i = b * 256 + threadIdx.x;
        if (i < N_EDGES) {
            int c = col[i];
            int pos = atomicAdd(&cursor[c], 1);
            if (pos < 64) srcs[((size_t)c << 6) + pos] = row[i];   // clamp: P(deg>=64)~1e-25
        }
    } else {
        int i = (b - HIST_BLOCKS) * 256 + threadIdx.x;  // 0 .. 32767
        int n = i >> 8, k = i & 255;
        Wt[n * IN_DIM + k] = f2bf(W[(size_t)k * HID + n]);
    }
}

// ===========================================================================
// FALLBACK PATH (verified): hist + 3-step scan + CSR fill
// ===========================================================================
__global__ __launch_bounds__(256) void hist_prepw_kernel(const int* __restrict__ col, int* cnt,
                                                         const float* __restrict__ W, ushort* Wt) {
    int b = blockIdx.x;
    if (b < HIST_BLOCKS) {
        int i = b * 256 + threadIdx.x;
        if (i < N_EDGES) atomicAdd(&cnt[col[i]], 1);
    } else {
        int i = (b - HIST_BLOCKS) * 256 + threadIdx.x;  // 0 .. 32767
        int n = i >> 8, k = i & 255;
        Wt[n * IN_DIM + k] = f2bf(W[(size_t)k * HID + n]);
    }
}

__global__ __launch_bounds__(256) void scan_blocksum_kernel(const int* __restrict__ cnt,
                                                            int* blocksums, int n) {
    __shared__ int s[256];
    int i = blockIdx.x * 256 + threadIdx.x;
    s[threadIdx.x] = (i < n) ? cnt[i] : 0;
    __syncthreads();
    for (int off = 128; off > 0; off >>= 1) {
        if (threadIdx.x < off) s[threadIdx.x] += s[threadIdx.x + off];
        __syncthreads();
    }
    if (threadIdx.x == 0) blocksums[blockIdx.x] = s[0];
}

__global__ __launch_bounds__(256) void scan_top_kernel(int* blocksums, int nb) {
    __shared__ int s[256];
    int t = threadIdx.x;
    int v = (t < nb) ? blocksums[t] : 0;
    s[t] = v;
    __syncthreads();
    for (int off = 1; off < 256; off <<= 1) {
        int x = 0;
        if (t >= off) x = s[t - off];
        __syncthreads();
        if (t >= off) s[t] += x;
        __syncthreads();
    }
    if (t < nb) blocksums[t] = s[t] - v;   // exclusive
}

__global__ __launch_bounds__(256) void scan_final_kernel(const int* __restrict__ cnt,
                                                         const int* __restrict__ blocksums,
                                                         int* rowptr, int* cursor,
                                                         float* dis, int n) {
    __shared__ int s[256];
    int t = threadIdx.x;
    int i = blockIdx.x * 256 + t;
    int v = (i < n) ? cnt[i] : 0;
    s[t] = v;
    __syncthreads();
    for (int off = 1; off < 256; off <<= 1) {
        int x = 0;
        if (t >= off) x = s[t - off];
        __syncthreads();
        if (t >= off) s[t] += x;
        __syncthreads();
    }
    if (i < n) {
        int excl = blocksums[blockIdx.x] + s[t] - v;
        rowptr[i] = excl;
        cursor[i] = excl;
        dis[i] = rsqrtf((float)v + 1.0f);   // +1 = self loop
    }
    if (i == n - 1) rowptr[n] = N_EDGES;
}

__global__ __launch_bounds__(256) void fill_kernel(const int* __restrict__ row,
                                                   const int* __restrict__ col,
                                                   int* cursor, int* srcs, int E) {
    int i = blockIdx.x * 256 + threadIdx.x;
    if (i < E) {
        int c = col[i];
        int pos = atomicAdd(&cursor[c], 1);
        srcs[pos] = row[i];
    }
}

// ---------------------------------------------------------------------------
// GEMM via MFMA: h[M,128](bf16) = x[M,256] @ W[256,128].
// BM=64 (session-best r4 config; BM=128 measured neutral-negative twice).
// If deg != nullptr: epilogue scales row r by rsqrt(deg[r]+1)  (dis folding).
// ---------------------------------------------------------------------------
#define LDA 40

__global__ __launch_bounds__(256) void gemm_kernel(const float* __restrict__ x,
                                                   const ushort* __restrict__ Wt,
                                                   ushort* __restrict__ h2, int M,
                                                   const int* __restrict__ deg) {
    __shared__ ushort As[64][LDA];
    __shared__ ushort Bs[128][LDA];
    const int t = threadIdx.x;
    const int row0 = blockIdx.x * 64;
    const int wave = t >> 6, lane = t & 63;
    const int lrow = lane & 15, quad = lane >> 4;

    f32x4 acc[8];
    #pragma unroll
    for (int c = 0; c < 8; c++) acc[c] = (f32x4){0.f, 0.f, 0.f, 0.f};

    const int arow = t >> 2, aq = t & 3;   // A staging: row 0..63, 8-float chunk 0..3
    const int bn = t >> 1, bh = t & 1;     // B staging: n 0..127, 16-elem half

    for (int k0 = 0; k0 < IN_DIM; k0 += 32) {
        // stage A: 64 rows x 32 k, fp32 -> bf16
        {
            int gr = row0 + arow;
            uint4 pk = make_uint4(0, 0, 0, 0);
            if (gr < M) {
                const float* src = x + (size_t)gr * IN_DIM + k0 + aq * 8;
                float4 f0 = *(const float4*)src;
                float4 f1 = *(const float4*)(src + 4);
                pk.x = f2bf(f0.x) | ((uint)f2bf(f0.y) << 16);
                pk.y = f2bf(f0.z) | ((uint)f2bf(f0.w) << 16);
                pk.z = f2bf(f1.x) | ((uint)f2bf(f1.y) << 16);
                pk.w = f2bf(f1.z) | ((uint)f2bf(f1.w) << 16);
            }
            *(uint4*)&As[arow][aq * 8] = pk;
        }
        // stage B: 128 n-rows x 32 k from Wt[n][k] (already bf16, k-contiguous)
        {
            const uint4* src = (const uint4*)(Wt + (size_t)bn * IN_DIM + k0 + bh * 16);
            *(uint4*)&Bs[bn][bh * 16]     = src[0];
            *(uint4*)&Bs[bn][bh * 16 + 8] = src[1];
        }
        __syncthreads();

        // A frag: A[m=lane&15][k=quad*8+j]; B frag: B[n=lane&15][k=quad*8+j]
        bf16x8 af = *(const bf16x8*)&As[wave * 16 + lrow][quad * 8];
        #pragma unroll
        for (int c = 0; c < 8; c++) {
            bf16x8 bfr = *(const bf16x8*)&Bs[c * 16 + lrow][quad * 8];
            acc[c] = __builtin_amdgcn_mfma_f32_16x16x32_bf16(af, bfr, acc[c], 0, 0, 0);
        }
        __syncthreads();
    }

    // epilogue: C/D layout col=lane&15, row=quad*4+reg; optional dis-fold; store bf16
    float disr[4];
    #pragma unroll
    for (int r = 0; r < 4; r++) {
        int gr = row0 + wave * 16 + quad * 4 + r;
        float sc = 1.0f;
        if (deg != nullptr) {
            int d = (gr < M) ? deg[gr] : 0;
            sc = rsqrtf((float)d + 1.0f);
        }
        disr[r] = sc;
    }
    #pragma unroll
    for (int c = 0; c < 8; c++) {
        #pragma unroll
        for (int r = 0; r < 4; r++) {
            int gr = row0 + wave * 16 + quad * 4 + r;
            if (gr < M) h2[(size_t)gr * HID + c * 16 + lrow] = f2bf(acc[c][r] * disr[r]);
        }
    }
}

// ---------------------------------------------------------------------------
// FAST gather (r4-verified, session-best): 16-deep dependency-free row-load
// bursts. Per node: bucket indices in registers (lane e holds srcs[node*64+e]);
// per burst 16 shfl'd+guarded indices then 16 back-to-back row loads, then
// one consume pass. ~17 rows in flight per wave (incl. self row).
// 1024 blocks (2048 regresses ~+16us — r8 datum). h2 pre-scaled by dis.
// ---------------------------------------------------------------------------
#define GATHERC_BLOCKS 1024

__global__ __launch_bounds__(256) void gatherc_kernel(const int* __restrict__ deg,
                                                      const int* __restrict__ srcs,
                                                      const uint* __restrict__ h2,
                                                      float* __restrict__ out,
                                                      float* colsum, float* colsumsq) {
    const int wave = threadIdx.x >> 6, lane = threadIdx.x & 63;
    float s0 = 0.f, s1 = 0.f, q0 = 0.f, q1 = 0.f;

    for (int node = blockIdx.x * 4 + wave; node < N_NODES; node += GATHERC_BLOCKS * 4) {
        int d = deg[node]; if (d > 64) d = 64;      // memory-safety clamp
        int idx = srcs[((size_t)node << 6) + lane]; // lane e holds neighbor e
        uint u = h2[(size_t)node * 64 + lane];      // self row, joins the flight
        float dn = rsqrtf((float)d + 1.0f);
        float ax = bflo(u), ay = bfhi(u);           // self-loop (pre-scaled)

        for (int e = 0; e < d; e += 16) {
            uint v[16];
            #pragma unroll
            for (int j = 0; j < 16; j++) {          // issue 16 loads, zero deps between
                int ej = e + j;
                int a = __shfl(idx, ej & 63);
                a = (ej < d) ? a : 0;               // d is wave-uniform -> scalar select
                v[j] = h2[(size_t)a * 64 + lane];
            }
            #pragma unroll
            for (int j = 0; j < 16; j++) {          // consume after all issued
                uint vv = ((e + j) < d) ? v[j] : 0u;   // uniform cond
                ax += bflo(vv); ay += bfhi(vv);
            }
        }

        ax *= dn; ay *= dn;
        ((float2*)(out + (size_t)node * HID))[lane] = make_float2(ax, ay);
        s0 += ax; s1 += ay;
        q0 = fmaf(ax, ax, q0); q1 = fmaf(ay, ay, q1);
    }

    // block-level stat reduction: cols 2*lane(+1) per lane, 4 waves
    __shared__ float rs[4][HID];
    __shared__ float rq[4][HID];
    rs[wave][lane * 2] = s0; rs[wave][lane * 2 + 1] = s1;
    rq[wave][lane * 2] = q0; rq[wave][lane * 2 + 1] = q1;
    __syncthreads();
    int t = threadIdx.x;
    if (t < HID) {
        float s = rs[0][t] + rs[1][t] + rs[2][t] + rs[3][t];
        float q = rq[0][t] + rq[1][t] + rq[2][t] + rq[3][t];
        atomicAdd(&colsum[t], s);
        atomicAdd(&colsumsq[t], q);
    }
}

// ---------------------------------------------------------------------------
// FALLBACK gather (verified): per-edge dis loads, 8-deep MLP.
// ---------------------------------------------------------------------------
#define GATHER_BLOCKS 1024

__global__ __launch_bounds__(256) void gather_kernel(const int* __restrict__ rowptr,
                                                     const int* __restrict__ srcs,
                                                     const float* __restrict__ dis,
                                                     const uint* __restrict__ h2,   // 64 uints/row
                                                     float* __restrict__ out,
                                                     float* colsum, float* colsumsq) {
    const int wave = threadIdx.x >> 6, lane = threadIdx.x & 63;
    float s0 = 0.f, s1 = 0.f, q0 = 0.f, q1 = 0.f;

    for (int node = blockIdx.x * 4 + wave; node < N_NODES; node += GATHER_BLOCKS * 4) {
        int beg = rowptr[node], end = rowptr[node + 1];
        float dn = dis[node];
        uint u = h2[(size_t)node * 64 + lane];
        float ax = bflo(u) * dn, ay = bfhi(u) * dn;    // self-loop (pre dn factor)

        int e = beg;
        for (; e + 8 <= end; e += 8) {
            int sa = srcs[e],     sb = srcs[e + 1], sc = srcs[e + 2], sd = srcs[e + 3];
            int se = srcs[e + 4], sf = srcs[e + 5], sg = srcs[e + 6], sh = srcs[e + 7];
            uint ua = h2[(size_t)sa * 64 + lane];
            uint ub = h2[(size_t)sb * 64 + lane];
            uint uc = h2[(size_t)sc * 64 + lane];
            uint ud = h2[(size_t)sd * 64 + lane];
            uint ue = h2[(size_t)se * 64 + lane];
            uint uf = h2[(size_t)sf * 64 + lane];
            uint ug = h2[(size_t)sg * 64 + lane];
            uint uh = h2[(size_t)sh * 64 + lane];
            float da = dis[sa], db = dis[sb], dc = dis[sc], dd = dis[sd];
            float de = dis[se], df = dis[sf], dg = dis[sg], dh = dis[sh];
            ax = fmaf(bflo(ua), da, ax); ay = fmaf(bfhi(ua), da, ay);
            ax = fmaf(bflo(ub), db, ax); ay = fmaf(bfhi(ub), db, ay);
            ax = fmaf(bflo(uc), dc, ax); ay = fmaf(bfhi(uc), dc, ay);
            ax = fmaf(bflo(ud), dd, ax); ay = fmaf(bfhi(ud), dd, ay);
            ax = fmaf(bflo(ue), de, ax); ay = fmaf(bfhi(ue), de, ay);
            ax = fmaf(bflo(uf), df, ax); ay = fmaf(bfhi(uf), df, ay);
            ax = fmaf(bflo(ug), dg, ax); ay = fmaf(bfhi(ug), dg, ay);
            ax = fmaf(bflo(uh), dh, ax); ay = fmaf(bfhi(uh), dh, ay);
        }
        for (; e + 4 <= end; e += 4) {
            int sa = srcs[e], sb = srcs[e + 1], sc = srcs[e + 2], sd = srcs[e + 3];
            uint ua = h2[(size_t)sa * 64 + lane];
            uint ub = h2[(size_t)sb * 64 + lane];
            uint uc = h2[(size_t)sc * 64 + lane];
            uint ud = h2[(size_t)sd * 64 + lane];
            float da = dis[sa], db = dis[sb], dc = dis[sc], dd = dis[sd];
            ax = fmaf(bflo(ua), da, ax); ay = fmaf(bfhi(ua), da, ay);
            ax = fmaf(bflo(ub), db, ax); ay = fmaf(bfhi(ub), db, ay);
            ax = fmaf(bflo(uc), dc, ax); ay = fmaf(bfhi(uc), dc, ay);
            ax = fmaf(bflo(ud), dd, ax); ay = fmaf(bfhi(ud), dd, ay);
        }
        for (; e < end; e++) {
            int s = srcs[e];
            uint uv = h2[(size_t)s * 64 + lane];
            float ds = dis[s];
            ax = fmaf(bflo(uv), ds, ax); ay = fmaf(bfhi(uv), ds, ay);
        }
        ax *= dn; ay *= dn;
        ((float2*)(out + (size_t)node * HID))[lane] = make_float2(ax, ay);
        s0 += ax; s1 += ay;
        q0 = fmaf(ax, ax, q0); q1 = fmaf(ay, ay, q1);
    }

    __shared__ float rs[4][HID];
    __shared__ float rq[4][HID];
    rs[wave][lane * 2] = s0; rs[wave][lane * 2 + 1] = s1;
    rq[wave][lane * 2] = q0; rq[wave][lane * 2 + 1] = q1;
    __syncthreads();
    int t = threadIdx.x;
    if (t < HID) {
        float s = rs[0][t] + rs[1][t] + rs[2][t] + rs[3][t];
        float q = rq[0][t] + rq[1][t] + rq[2][t] + rq[3][t];
        atomicAdd(&colsum[t], s);
        atomicAdd(&colsumsq[t], q);
    }
}

// ---------------------------------------------------------------------------
// BN (training stats, biased var) + ReLU, in place. (bias b cancels in BN)
// ---------------------------------------------------------------------------
__global__ __launch_bounds__(256) void bn_relu_kernel(float* __restrict__ out,
                                                      const float* __restrict__ colsum,
                                                      const float* __restrict__ colsumsq,
                                                      const float* __restrict__ gamma,
                                                      const float* __restrict__ beta, int M) {
    size_t i = (size_t)blockIdx.x * 256 + threadIdx.x;
    size_t total = (size_t)M * (HID / 4);
    if (i >= total) return;
    int c4 = (int)((i & (HID / 4 - 1)) * 4);
    float4 v = ((const float4*)out)[i];
    float vv[4] = {v.x, v.y, v.z, v.w};
    float res[4];
    const float invN = 1.0f / (float)M;
    #pragma unroll
    for (int j = 0; j < 4; j++) {
        int c = c4 + j;
        float mean = colsum[c] * invN;
        float var  = colsumsq[c] * invN - mean * mean;
        var = fmaxf(var, 0.0f);
        float sc = gamma[c] * rsqrtf(var + BN_EPS);
        res[j] = fmaxf(0.0f, (vv[j] - mean) * sc + beta[c]);
    }
    ((float4*)out)[i] = make_float4(res[0], res[1], res[2], res[3]);
}

// ---------------------------------------------------------------------------
extern "C" void kernel_launch(void* const* d_in, const int* in_sizes, int n_in,
                              void* d_out, int out_size, void* d_ws, size_t ws_size,
                              hipStream_t stream) {
    const float* x     = (const float*)d_in[0];
    const int*   ei    = (const int*)  d_in[1];   // [2,E] flat: row(src) then col(dst)
    const float* W     = (const float*)d_in[2];
    // d_in[3] = b: cancels inside BatchNorm -> unused
    const float* gamma = (const float*)d_in[4];
    const float* beta  = (const float*)d_in[5];
    float* out = (float*)d_out;

    const int* row = ei;
    const int* col = ei + N_EDGES;

    const size_t FAST_NEED = (size_t)6466816u * 4u;   // 25.87 MB

    if (ws_size >= FAST_NEED) {
        // ---------- fast path: bucket CSR, dis folded into GEMM ----------
        int*    cursor   = (int*)d_ws;                       // [50000] -> deg after fill
        int*    srcs     = (int*)d_ws + 50176;               // [50000*64] bucket CSR
        ushort* Wt       = (ushort*)((int*)d_ws + 3250176);  // [128*256] bf16
        ushort* h2       = (ushort*)((int*)d_ws + 3266560);  // [50000*128] bf16, pre-scaled
        float*  colsum   = (float*)d_ws + 6466560;           // [128]
        float*  colsumsq = (float*)d_ws + 6466688;           // [128]

        zero_kernel<<<(N_NODES + 255) / 256, 256, 0, stream>>>(cursor, colsum, N_NODES);

        fillb_prepw_kernel<<<HIST_BLOCKS + PREPW_BLOCKS, 256, 0, stream>>>(row, col, cursor,
                                                                           srcs, W, Wt);

        gemm_kernel<<<(N_NODES + 63) / 64, 256, 0, stream>>>(x, Wt, h2, N_NODES, cursor);

        gatherc_kernel<<<GATHERC_BLOCKS, 256, 0, stream>>>(cursor, srcs, (const uint*)h2, out,
                                                           colsum, colsumsq);

        size_t total = (size_t)N_NODES * (HID / 4);
        bn_relu_kernel<<<(int)((total + 255) / 256), 256, 0, stream>>>(out, colsum, colsumsq,
                                                                       gamma, beta, N_NODES);
    } else {
        // ---------- fallback: verified CSR path ----------
        int*    cnt       = (int*)d_ws;                        // [50000]
        float*  dis       = (float*)d_ws + 50000;              // [50000]
        int*    rowptr    = (int*)d_ws + 100000;               // [50001]
        int*    cursor    = (int*)d_ws + 150016;               // [50000]
        int*    blocksums = (int*)d_ws + 200016;               // [256]
        int*    srcs      = (int*)d_ws + 200272;               // [600000]
        ushort* Wt        = (ushort*)((int*)d_ws + 800272);    // [128*256] bf16
        ushort* h2        = (ushort*)((int*)d_ws + 816656);    // [50000*128] bf16
        float*  colsum    = (float*)d_ws + 4016656;            // [128]
        float*  colsumsq  = (float*)d_ws + 4016784;            // [128]

        zero_kernel<<<(N_NODES + 255) / 256, 256, 0, stream>>>(cnt, colsum, N_NODES);

        hist_prepw_kernel<<<HIST_BLOCKS + PREPW_BLOCKS, 256, 0, stream>>>(col, cnt, W, Wt);

        scan_blocksum_kernel<<<SCAN_BLOCKS, 256, 0, stream>>>(cnt, blocksums, N_NODES);
        scan_top_kernel<<<1, 256, 0, stream>>>(blocksums, SCAN_BLOCKS);
        scan_final_kernel<<<SCAN_BLOCKS, 256, 0, stream>>>(cnt, blocksums, rowptr, cursor, dis,
                                                           N_NODES);

        fill_kernel<<<HIST_BLOCKS, 256, 0, stream>>>(row, col, cursor, srcs, N_EDGES);

        gemm_kernel<<<(N_NODES + 63) / 64, 256, 0, stream>>>(x, Wt, h2, N_NODES, nullptr);

        gather_kernel<<<GATHER_BLOCKS, 256, 0, stream>>>(rowptr, srcs, dis, (const uint*)h2, out,
                                                         colsum, colsumsq);

        size_t total = (size_t)N_NODES * (HID / 4);
        bn_relu_kernel<<<(int)((total + 255) / 256), 256, 0, stream>>>(out, colsum, colsumsq,
                                                                       gamma, beta, N_NODES);
    }
}